// Round 5
// baseline (197.244 us; speedup 1.0000x reference)
//
#include <hip/hip_runtime.h>
#include <hip/hip_bf16.h>
#include <math.h>

// Problem constants
#define NB   2048     // batch
#define ND   1024     // dim (elements; == bytes per row in fp8)
#define INV_TEMP 10.0f
#define LAMBDA_CS 0.5f
#define GEMM_BLOCKS 1552

using floatx4 = __attribute__((ext_vector_type(4))) float;

__device__ __forceinline__ int pack4_fp8(float a, float b, float c, float d) {
  int p = __builtin_amdgcn_cvt_pk_fp8_f32(a, b, 0, false);   // bytes 0,1
  p     = __builtin_amdgcn_cvt_pk_fp8_f32(c, d, p, true);    // bytes 2,3
  return p;
}

// ---------------------------------------------------------------------------
// Kernel 1: one WAVE per (array t, row b). No block-wide load barrier, no
// multi-value butterflies. Lane i owns contiguous k = 16i..16i+15.
//   wave t normalizes row b of array t -> fp8 M[(t*NB+b)*ND], publishes 1/norm
//   to LDS; waves 2,3 additionally hold raw e,k rows and compute the cs-reg
//   norms after a single barrier. Also zeroes rowsum/counter for kernel 2.
// ---------------------------------------------------------------------------
__global__ __launch_bounds__(256) void k_prep(
    const float* __restrict__ e, const float* __restrict__ k,
    const float* __restrict__ et, const float* __restrict__ kt,
    const float* __restrict__ ratios,
    unsigned char* __restrict__ M, float* __restrict__ reg2,
    float* __restrict__ rowsum, unsigned* __restrict__ counter)
{
  const int b = blockIdx.x, tid = threadIdx.x;
  const int wv = tid >> 6, lane = tid & 63;

  if (b < 16) rowsum[b * 256 + tid] = 0.0f;
  if (b == 16 && tid == 0) *counter = 0u;

  const float* src = (wv == 0) ? e : (wv == 1) ? k : (wv == 2) ? et : kt;
  const float4* row = (const float4*)(src + (size_t)b * ND);
  float4 v0 = row[lane * 4 + 0], v1 = row[lane * 4 + 1];
  float4 v2 = row[lane * 4 + 2], v3 = row[lane * 4 + 3];

  // waves 2,3 also need raw e,k rows (issue loads early; L2-hot)
  float4 e0, e1, e2, e3, k0, k1, k2, k3;
  if (wv >= 2) {
    const float4* re = (const float4*)(e + (size_t)b * ND);
    const float4* rk = (const float4*)(k + (size_t)b * ND);
    e0 = re[lane * 4 + 0]; e1 = re[lane * 4 + 1];
    e2 = re[lane * 4 + 2]; e3 = re[lane * 4 + 3];
    k0 = rk[lane * 4 + 0]; k1 = rk[lane * 4 + 1];
    k2 = rk[lane * 4 + 2]; k3 = rk[lane * 4 + 3];
  }

  float ss = v0.x*v0.x + v0.y*v0.y + v0.z*v0.z + v0.w*v0.w
           + v1.x*v1.x + v1.y*v1.y + v1.z*v1.z + v1.w*v1.w
           + v2.x*v2.x + v2.y*v2.y + v2.z*v2.z + v2.w*v2.w
           + v3.x*v3.x + v3.y*v3.y + v3.z*v3.z + v3.w*v3.w;
  #pragma unroll
  for (int o = 1; o < 64; o <<= 1) ss += __shfl_xor(ss, o);
  const float inv = 1.0f / sqrtf(ss);

  __shared__ float s_inv[4];
  if (lane == 0) s_inv[wv] = inv;

  // pack 16 contiguous fp8 bytes, single b128 store per lane
  int4 o4;
  o4.x = pack4_fp8(v0.x*inv, v0.y*inv, v0.z*inv, v0.w*inv);
  o4.y = pack4_fp8(v1.x*inv, v1.y*inv, v1.z*inv, v1.w*inv);
  o4.z = pack4_fp8(v2.x*inv, v2.y*inv, v2.z*inv, v2.w*inv);
  o4.w = pack4_fp8(v3.x*inv, v3.y*inv, v3.z*inv, v3.w*inv);
  *(int4*)(M + ((size_t)wv * NB + b) * ND + lane * 16) = o4;

  __syncthreads();

  if (wv >= 2) {
    const float ie = s_inv[0], ik = s_inv[1];
    const float r0 = ratios[b];
    const float ra = (wv == 2) ? r0 : 1.0f - r0;   // coefficient on e
    const float rb = 1.0f - ra;                    // coefficient on k
    float a = 0.f;
    #define REG_ACC(vv, ee, kk) { \
      float d; \
      d = vv.x*inv - (ra*(ee.x*ie) + rb*(kk.x*ik)); a += d*d; \
      d = vv.y*inv - (ra*(ee.y*ie) + rb*(kk.y*ik)); a += d*d; \
      d = vv.z*inv - (ra*(ee.z*ie) + rb*(kk.z*ik)); a += d*d; \
      d = vv.w*inv - (ra*(ee.w*ie) + rb*(kk.w*ik)); a += d*d; }
    REG_ACC(v0, e0, k0) REG_ACC(v1, e1, k1) REG_ACC(v2, e2, k2) REG_ACC(v3, e3, k3)
    #undef REG_ACC
    #pragma unroll
    for (int o = 1; o < 64; o <<= 1) a += __shfl_xor(a, o);
    if (lane == 0) reg2[b * 2 + (wv - 2)] = sqrtf(a);
  }
}

// ---------------------------------------------------------------------------
// Kernel 2: fused fp8 NT-GEMM + exp + row-sum + diag + last-block reduction.
//   mfma_f32_16x16x32_fp8_fp8, BK=32 (32 K-iterations) — R2's exact proven
//   iteration structure (m145: fp8 at this structure = +14% over bf16).
//   Staging: 4 KB per tile, 1 global_load_lds(16B) per wave per matrix/iter.
//   Fragment ds_read_b64 with 16B-half XOR key1(row)=(row>>2)&1 -> <=2-way.
//   Symmetric left half: only upper-tri blocks; mirrored column credit.
// ---------------------------------------------------------------------------
__global__ __launch_bounds__(256) void k_gemm(
    const unsigned char* __restrict__ M,
    float* __restrict__ rowsum,        // [4096], zeroed by k_prep
    float* __restrict__ diag,          // [2][4][2048]; [1][0] unused (mirror)
    const float* __restrict__ reg2,    // [2*NB]
    unsigned* __restrict__ counter,
    float* __restrict__ out)
{
  __shared__ __align__(16) unsigned char As[128 * 32];
  __shared__ __align__(16) unsigned char Bs[128 * 32];
  __shared__ float redR[256];
  __shared__ float redC[256];
  __shared__ unsigned s_rank;

  // decode (bx, by): 1024 right-half blocks + 528 upper-tri left-half blocks
  int bx, by;
  {
    int idx = blockIdx.x;
    if (idx < 1024) { by = idx >> 5; bx = 32 + (idx & 31); }
    else {
      int t = idx - 1024; by = 0;
      while (t >= 32 - by) { t -= 32 - by; ++by; }
      bx = by + t;
    }
  }
  const bool sym = (bx < 32) && (bx > by);
  const int j0 = bx * 128;
  const int i0 = by * 128;

  const int tid  = threadIdx.x;
  const int wave = tid >> 6;
  const int lane = tid & 63;
  const int q = lane >> 4;       // quad 0..3
  const int m = lane & 15;       // row/col within 16
  const int wrow = (wave >> 1) * 64;
  const int wcol = (wave & 1) * 64;

  floatx4 acc[4][4] = {};

  // staging: wave w stages rows [32w, 32w+32) of A and B.
  // lane l -> row-in-chunk l>>1; 16B half h = (l&1) ^ key1(row), key1=(row>>2)&1.
  const int ric  = lane >> 1;
  const int half = (lane & 1) ^ ((ric >> 2) & 1);
  const size_t sgoff = (size_t)(wave * 32 + ric) * ND + half * 16;

  const unsigned char* gA = M + (size_t)i0 * ND;
  const unsigned char* gB = M + (size_t)j0 * ND;

  // fragment LDS byte offsets: chunk q (8B) of row -> row*32 +
  //   (((q>>1) ^ key1(row))*16) + (q&1)*8
  int aoff[4], boff[4];
  #pragma unroll
  for (int x = 0; x < 4; ++x) {
    const int ra = wrow + x * 16 + m;
    aoff[x] = ra * 32 + (((q >> 1) ^ ((ra >> 2) & 1)) * 16) + (q & 1) * 8;
    const int rb = wcol + x * 16 + m;
    boff[x] = rb * 32 + (((q >> 1) ^ ((rb >> 2) & 1)) * 16) + (q & 1) * 8;
  }

  for (int it = 0; it < 32; ++it) {
    const int koff = it * 32;
    __syncthreads();
    __builtin_amdgcn_global_load_lds(
        (const __attribute__((address_space(1))) unsigned int*)(gA + sgoff + koff),
        (__attribute__((address_space(3))) unsigned int*)&As[wave * 1024], 16, 0, 0);
    __builtin_amdgcn_global_load_lds(
        (const __attribute__((address_space(1))) unsigned int*)(gB + sgoff + koff),
        (__attribute__((address_space(3))) unsigned int*)&Bs[wave * 1024], 16, 0, 0);
    __syncthreads();

    long af[4], bf[4];
    #pragma unroll
    for (int x = 0; x < 4; ++x) {
      af[x] = *(const long*)&As[aoff[x]];
      bf[x] = *(const long*)&Bs[boff[x]];
    }
    #pragma unroll
    for (int mi = 0; mi < 4; ++mi)
      #pragma unroll
      for (int ni = 0; ni < 4; ++ni)
        acc[mi][ni] = __builtin_amdgcn_mfma_f32_16x16x32_fp8_fp8(
            af[mi], bf[ni], acc[mi][ni], 0, 0, 0);
  }

  // Epilogue. C/D layout (dtype-independent): col = lane&15, row = q*4 + reg
  float colAcc[4] = {0.f, 0.f, 0.f, 0.f};
  #pragma unroll
  for (int mi = 0; mi < 4; ++mi) {
    #pragma unroll
    for (int r = 0; r < 4; ++r) {
      const int ig = i0 + wrow + mi * 16 + q * 4 + r;
      float s = 0.f;
      #pragma unroll
      for (int ni = 0; ni < 4; ++ni) {
        float v = __expf(acc[mi][ni][r] * INV_TEMP);
        s += v;
        colAcc[ni] += v;
        const int jg = j0 + wcol + ni * 16 + m;
        if ((jg & (NB - 1)) == (ig & (NB - 1))) {
          diag[(((ig >> 11) << 2) + (jg >> 11)) * NB + (ig & (NB - 1))] = v;
        }
      }
      s += __shfl_xor(s, 1);
      s += __shfl_xor(s, 2);
      s += __shfl_xor(s, 4);
      s += __shfl_xor(s, 8);
      if (m == 0) redR[(wave & 1) * 128 + wrow + mi * 16 + q * 4 + r] = s;
    }
  }
  #pragma unroll
  for (int ni = 0; ni < 4; ++ni) {
    float c = colAcc[ni];
    c += __shfl_xor(c, 16);
    c += __shfl_xor(c, 32);
    if (q == 0) redC[(wave >> 1) * 128 + wcol + ni * 16 + m] = c;
  }
  __syncthreads();
  if (tid < 128) {
    atomicAdd(&rowsum[i0 + tid], redR[tid] + redR[128 + tid]);
    if (sym)
      atomicAdd(&rowsum[j0 + tid], redC[tid] + redC[128 + tid]);
  }

  // completion: last finished block computes the final scalars
  __syncthreads();
  if (tid == 0) {
    __threadfence();
    s_rank = __hip_atomic_fetch_add(counter, 1u, __ATOMIC_ACQ_REL,
                                    __HIP_MEMORY_SCOPE_AGENT);
  }
  __syncthreads();
  if (s_rank == GEMM_BLOCKS - 1) {
    float l = 0.f, g = 0.f;
    #pragma unroll
    for (int i = 0; i < 8; ++i) {
      const int n = tid + i * 256;
      float se = __hip_atomic_load(&rowsum[n],        __ATOMIC_RELAXED, __HIP_MEMORY_SCOPE_AGENT);
      float sk = __hip_atomic_load(&rowsum[2048 + n], __ATOMIC_RELAXED, __HIP_MEMORY_SCOPE_AGENT);
      float d_ee  = __hip_atomic_load(&diag[0 * NB + n], __ATOMIC_RELAXED, __HIP_MEMORY_SCOPE_AGENT);
      float d_ek  = __hip_atomic_load(&diag[1 * NB + n], __ATOMIC_RELAXED, __HIP_MEMORY_SCOPE_AGENT);
      float d_eet = __hip_atomic_load(&diag[2 * NB + n], __ATOMIC_RELAXED, __HIP_MEMORY_SCOPE_AGENT);
      float d_ekt = __hip_atomic_load(&diag[3 * NB + n], __ATOMIC_RELAXED, __HIP_MEMORY_SCOPE_AGENT);
      float d_kk  = __hip_atomic_load(&diag[5 * NB + n], __ATOMIC_RELAXED, __HIP_MEMORY_SCOPE_AGENT);
      float d_ket = __hip_atomic_load(&diag[6 * NB + n], __ATOMIC_RELAXED, __HIP_MEMORY_SCOPE_AGENT);
      float d_kkt = __hip_atomic_load(&diag[7 * NB + n], __ATOMIC_RELAXED, __HIP_MEMORY_SCOPE_AGENT);
      float num_e = d_ek + d_eet + d_ekt;
      float den_e = se - d_ee;
      float num_k = d_ek + d_ket + d_kkt;   // k.e diag == e.k diag (mirror)
      float den_k = sk - d_kk;
      l += logf(den_e / num_e) + logf(den_k / num_k);
      g += reg2[2 * n] + reg2[2 * n + 1];
    }
    #pragma unroll
    for (int o = 1; o < 64; o <<= 1) { l += __shfl_xor(l, o); g += __shfl_xor(g, o); }
    if ((tid & 63) == 0) { redR[tid >> 6] = l; redC[tid >> 6] = g; }
    __syncthreads();
    if (tid == 0) {
      float contrastive = (redR[0] + redR[1] + redR[2] + redR[3]) * (1.0f / (2.0f * NB));
      float cs = (redC[0] + redC[1] + redC[2] + redC[3]) * (1.0f / NB);
      out[0] = contrastive + LAMBDA_CS * cs;
      out[1] = contrastive;
      out[2] = cs;
    }
  }
}

// ---------------------------------------------------------------------------
extern "C" void kernel_launch(void* const* d_in, const int* in_sizes, int n_in,
                              void* d_out, int out_size, void* d_ws, size_t ws_size,
                              hipStream_t stream) {
  const float* english = (const float*)d_in[0];
  const float* etok    = (const float*)d_in[1];
  const float* ktoe    = (const float*)d_in[2];
  const float* korean  = (const float*)d_in[3];
  const float* ratios  = (const float*)d_in[4];

  char* ws = (char*)d_ws;
  const size_t OFF_M    = 0;                                   // 8192*1024 = 8 MB
  const size_t OFF_RS   = OFF_M + (size_t)8192 * 1024;         // 4096*4
  const size_t OFF_DIAG = OFF_RS + 4096 * sizeof(float);       // 8*2048*4
  const size_t OFF_REG  = OFF_DIAG + 8 * NB * sizeof(float);   // 2*2048*4
  const size_t OFF_CNT  = OFF_REG + 2 * NB * sizeof(float);    // 4

  unsigned char* M    = (unsigned char*)(ws + OFF_M);
  float* rowsum       = (float*)(ws + OFF_RS);
  float* diag         = (float*)(ws + OFF_DIAG);
  float* reg2         = (float*)(ws + OFF_REG);
  unsigned* counter   = (unsigned*)(ws + OFF_CNT);

  k_prep<<<dim3(NB), 256, 0, stream>>>(english, korean, etok, ktoe, ratios,
                                       M, reg2, rowsum, counter);
  k_gemm<<<dim3(GEMM_BLOCKS), 256, 0, stream>>>(M, rowsum, diag, reg2,
                                                counter, (float*)d_out);
}